// Round 14
// baseline (124.018 us; speedup 1.0000x reference)
//
#include <hip/hip_runtime.h>
#include <math.h>

#define EPS_ 1e-10f
#define MARGIN 4e-3f

typedef __attribute__((ext_vector_type(8))) short sh8;
typedef __attribute__((ext_vector_type(4))) float fx4;

__device__ __forceinline__ bool betterf(float v, int i, float w, int j) {
    return (v > w) || (v == w && i < j);
}
__device__ __forceinline__ bool betterd(double v, int i, double w, int j) {
    return (v > w) || (v == w && i < j);
}
__device__ __forceinline__ unsigned short f2bf(float f) {   // RNE
    unsigned u = __float_as_uint(f);
    u += 0x7fffu + ((u >> 16) & 1u);
    return (unsigned short)(u >> 16);
}
__device__ __forceinline__ float bf2f(unsigned short h) {
    return __uint_as_float(((unsigned)h) << 16);
}
__device__ __forceinline__ void cvt4(const float4 v, uint2& hp, uint2& lp) {
    const unsigned short h0 = f2bf(v.x), h1 = f2bf(v.y), h2 = f2bf(v.z), h3 = f2bf(v.w);
    const unsigned short l0 = f2bf(v.x - bf2f(h0)), l1 = f2bf(v.y - bf2f(h1));
    const unsigned short l2 = f2bf(v.z - bf2f(h2)), l3 = f2bf(v.w - bf2f(h3));
    hp.x = h0 | ((unsigned)h1 << 16); hp.y = h2 | ((unsigned)h3 << 16);
    lp.x = l0 | ((unsigned)l1 << 16); lp.y = l2 | ((unsigned)l3 << 16);
}

// ---------------------------------------------------------------------------
// One-time W conversion into B-fragment layout, bf16 hi/lo (layout verified).
// wf[((s*4+t)*2+hl)*512 + l*8 + j]; lane l=n+16*bq holds W[k=s*32+bq*8+j][e=t*16+n].
// ---------------------------------------------------------------------------
__global__ __launch_bounds__(256)
void wconv(const float* __restrict__ W, unsigned short* __restrict__ wf)
{
    const int gid = blockIdx.x * 256 + threadIdx.x;   // dim*64
    const int e = gid & 63, k = gid >> 6;
    const int s = k >> 5, kk = k & 31, bq = kk >> 3, j = kk & 7;
    const int t = e >> 4, n = e & 15;
    const int l = n + 16 * bq;
    const float w = W[(size_t)k * 64 + e];
    const unsigned short hi = f2bf(w);
    const unsigned short lo = f2bf(w - bf2f(hi));
    const size_t base = ((size_t)s * 4 + t) * 2;
    wf[(base + 0) * 512 + l * 8 + j] = hi;
    wf[(base + 1) * 512 + l * 8 + j] = lo;
}

// ---------------------------------------------------------------------------
// Fused MFMA router, STREAM-COALESCED x staging:
// block = 256 thr = 4 waves; wave = 16 rows x 64 experts, full K.
// Per K-window (128 floats/row): wave loads its 16 rows as 8 float4-instrs,
// each instr = two 512B-contiguous runs (lanes 0-31 row A, 32-63 row B) ->
// near-stream request pattern, 8 x 1KB in flight. Converted to bf16 hi/lo in
// regs, written to wave-PRIVATE LDS with chunk-XOR swizzle
// (chunk = (s*4+q) ^ (row&15)) so fragment ds_read_b128 is conflict-free.
// NO barriers in the K loop (each wave reads only rows it staged).
// W fragments: per-step register prefetch (2 named sets, static parity).
// Grid = N/64 = 256 blocks.
// ---------------------------------------------------------------------------
#define KWIN 128
__global__ __launch_bounds__(256, 1)
void gemm_mfma(const float* __restrict__ x, const unsigned short* __restrict__ wfg,
               const float* __restrict__ b, int dim, int N,
               float* __restrict__ ts, int* __restrict__ sel,
               float* __restrict__ rzrow,
               int* __restrict__ nflags, int* __restrict__ flaglist)
{
    // [0,32K): buf0 (hi 16K | lo 16K), [32K,64K): buf1, [64K,64K+16.6K): slots
    __shared__ __align__(16) char smem[82176];

    const int tid  = threadIdx.x;
    const int lane = tid & 63;
    const int wv   = tid >> 6;
    const int r0   = blockIdx.x * 64;
    const int nwin = dim / KWIN;          // 16
    const int nks  = dim >> 5;            // 64

    const int m   = lane & 15;
    const int q   = lane >> 4;
    const int l31 = lane & 31;
    const int l5  = lane >> 5;
    const int lh  = l31 & 1;
    const int lc  = l31 >> 1;

    fx4 acc[4] = {};

    char* const base = smem;
    const unsigned short* wl8 = wfg + lane * 8;

    sh8 wAh[4], wAl[4], wBh[4], wBl[4];
#pragma unroll
    for (int te = 0; te < 4; ++te) {
        wAh[te] = __builtin_bit_cast(sh8, *(const int4*)(wl8 + (te * 2 + 0) * 512));
        wAl[te] = __builtin_bit_cast(sh8, *(const int4*)(wl8 + (te * 2 + 1) * 512));
    }

    // stage window 0 into buf0
    float4 xa[8];
#pragma unroll
    for (int i = 0; i < 8; ++i) {
        const int row = wv * 16 + i * 2 + l5;
        xa[i] = *(const float4*)(x + (size_t)(r0 + row) * dim + l31 * 4);
    }
#pragma unroll
    for (int i = 0; i < 8; ++i) {
        const int row = wv * 16 + i * 2 + l5;
        const int sc = lc ^ (row & 15);
        uint2 hp, lp; cvt4(xa[i], hp, lp);
        *(uint2*)(base + row * 256 + sc * 16 + lh * 8) = hp;
        *(uint2*)(base + 16384 + row * 256 + sc * 16 + lh * 8) = lp;
    }

    const int arow = wv * 16 + m;

#define WSTEP(S, CH, CL, PH, PL)                                                    \
    {                                                                               \
        const int ks = w * 4 + S;                                                   \
        if (ks + 1 < nks) {                                                         \
            const unsigned short* wk = wl8 + (size_t)(ks + 1) * 4096;               \
            _Pragma("unroll")                                                       \
            for (int te = 0; te < 4; ++te) {                                        \
                PH[te] = __builtin_bit_cast(sh8, *(const int4*)(wk + (te * 2 + 0) * 512)); \
                PL[te] = __builtin_bit_cast(sh8, *(const int4*)(wk + (te * 2 + 1) * 512)); \
            }                                                                       \
        }                                                                           \
        const int sc = (S * 4 + q) ^ m;                                             \
        const sh8 ah = __builtin_bit_cast(sh8,                                      \
            *(const int4*)(base + cb * 32768 + arow * 256 + sc * 16));              \
        const sh8 al = __builtin_bit_cast(sh8,                                      \
            *(const int4*)(base + cb * 32768 + 16384 + arow * 256 + sc * 16));      \
        _Pragma("unroll")                                                           \
        for (int te = 0; te < 4; ++te) {                                            \
            acc[te] = __builtin_amdgcn_mfma_f32_16x16x32_bf16(ah, CH[te], acc[te], 0, 0, 0); \
            acc[te] = __builtin_amdgcn_mfma_f32_16x16x32_bf16(ah, CL[te], acc[te], 0, 0, 0); \
            acc[te] = __builtin_amdgcn_mfma_f32_16x16x32_bf16(al, CH[te], acc[te], 0, 0, 0); \
        }                                                                           \
    }

    for (int w = 0; w < nwin; ++w) {
        const int cb = w & 1;
        const int tb = cb ^ 1;
        const bool more = (w + 1 < nwin);
        if (more) {
#pragma unroll
            for (int i = 0; i < 8; ++i) {
                const int row = wv * 16 + i * 2 + l5;
                xa[i] = *(const float4*)(x + (size_t)(r0 + row) * dim
                                           + (size_t)(w + 1) * KWIN + l31 * 4);
            }
        }
        WSTEP(0, wAh, wAl, wBh, wBl)
        WSTEP(1, wBh, wBl, wAh, wAl)
        WSTEP(2, wAh, wAl, wBh, wBl)
        WSTEP(3, wBh, wBl, wAh, wAl)
        if (more) {
#pragma unroll
            for (int i = 0; i < 8; ++i) {
                const int row = wv * 16 + i * 2 + l5;
                const int sc = lc ^ (row & 15);
                uint2 hp, lp; cvt4(xa[i], hp, lp);
                *(uint2*)(base + tb * 32768 + row * 256 + sc * 16 + lh * 8) = hp;
                *(uint2*)(base + tb * 32768 + 16384 + row * 256 + sc * 16 + lh * 8) = lp;
            }
        }
    }
#undef WSTEP

    // publish z (C layout: col=lane&15, row-in-16=(lane>>4)*4+i) then epilogue
    float* slots = (float*)(base + 65536);
#pragma unroll
    for (int te = 0; te < 4; ++te)
#pragma unroll
        for (int i = 0; i < 4; ++i)
            slots[(wv * 16 + q * 4 + i) * 65 + te * 16 + m] = acc[te][i];
    __syncthreads();

    const int e = lane;
    const float be = b[e];
    for (int rr = 0; rr < 16; ++rr) {
        const int lrow = wv * 16 + rr;
        const int row = r0 + lrow;
        const float z = slots[lrow * 65 + e] + be;

        float v1 = z, v2 = -3.4e38f;
        int i1 = e, i2 = 1 << 30;
#pragma unroll
        for (int mm = 1; mm < 64; mm <<= 1) {
            const float wva = __shfl_xor(v1, mm, 64); const int j1 = __shfl_xor(i1, mm, 64);
            const float wvb = __shfl_xor(v2, mm, 64); const int j2 = __shfl_xor(i2, mm, 64);
            if (betterf(wva, j1, v1, i1)) {
                float nv2; int ni2;
                if (betterf(v1, i1, wvb, j2)) { nv2 = v1; ni2 = i1; }
                else                          { nv2 = wvb; ni2 = j2; }
                v1 = wva; i1 = j1; v2 = nv2; i2 = ni2;
            } else if (betterf(wva, j1, v2, i2)) { v2 = wva; i2 = j1; }
        }

        float m3 = (e == i1 || e == i2) ? -3.4e38f : z;
#pragma unroll
        for (int mm = 1; mm < 64; mm <<= 1) m3 = fmaxf(m3, __shfl_xor(m3, mm, 64));

        const float ex = expf(z - v1);
        float ssum = ex;
#pragma unroll
        for (int mm = 1; mm < 64; mm <<= 1) ssum += __shfl_xor(ssum, mm, 64);
        const float inv = 1.0f / ssum;

        float sc2 = fminf(fmaxf(ex * inv, EPS_), 1.0f - EPS_);
        float srz = sc2 / (1.0f - sc2);
#pragma unroll
        for (int mm = 1; mm < 64; mm <<= 1) srz += __shfl_xor(srz, mm, 64);

        if (e == 0) {
            const float s1 = fminf(fmaxf(inv, EPS_), 1.0f - EPS_);
            const float s2 = fminf(fmaxf(expf(v2 - v1) * inv, EPS_), 1.0f - EPS_);
            ts[row * 2 + 0] = s1;
            ts[row * 2 + 1] = s2;
            sel[row * 2 + 0] = i1;
            sel[row * 2 + 1] = i2;
            rzrow[row] = srz;
            if ((v1 - v2) < MARGIN || (v2 - m3) < MARGIN) {
                const int slot2 = atomicAdd(nflags, 1);
                flaglist[slot2] = row;
            }
        }
    }
}

// ---------------------------------------------------------------------------
// fp64 recompute of flagged near-tie rows. 1024 thr = 64 e x 16 K-slices.
// ---------------------------------------------------------------------------
__global__ __launch_bounds__(1024)
void fixup(const float* __restrict__ x, const float* __restrict__ W,
           const float* __restrict__ b, int dim,
           const int* __restrict__ nflags, const int* __restrict__ flaglist,
           float* __restrict__ ts, int* __restrict__ sel)
{
    __shared__ double red[1024];
    const int tid = threadIdx.x;
    const int e = tid & 63;
    const int q = tid >> 6;              // 0..15
    const int nf = *nflags;
    const int slice = dim >> 4;          // 128

    for (int f = blockIdx.x; f < nf; f += gridDim.x) {
        const int row = flaglist[f];
        const float* xr = x + (size_t)row * dim;
        const int k0 = q * slice;
        double a0 = 0.0, a1 = 0.0, a2 = 0.0, a3 = 0.0;
        for (int k = k0; k < k0 + slice; k += 4) {
            a0 = fma((double)xr[k + 0], (double)W[(size_t)(k + 0) * 64 + e], a0);
            a1 = fma((double)xr[k + 1], (double)W[(size_t)(k + 1) * 64 + e], a1);
            a2 = fma((double)xr[k + 2], (double)W[(size_t)(k + 2) * 64 + e], a2);
            a3 = fma((double)xr[k + 3], (double)W[(size_t)(k + 3) * 64 + e], a3);
        }
        red[tid] = (a0 + a1) + (a2 + a3);
        __syncthreads();
        for (int st = 512; st >= 64; st >>= 1) {
            if (tid < st) red[tid] += red[tid + st];
            __syncthreads();
        }
        if (tid < 64) {
            const double z = red[tid] + (double)b[e];
            double v1 = z, v2 = -1e300;
            int i1 = e, i2 = 1 << 30;
#pragma unroll
            for (int mm = 1; mm < 64; mm <<= 1) {
                const double w1 = __shfl_xor(v1, mm, 64); const int j1 = __shfl_xor(i1, mm, 64);
                const double w2 = __shfl_xor(v2, mm, 64); const int j2 = __shfl_xor(i2, mm, 64);
                if (betterd(w1, j1, v1, i1)) {
                    double nv2; int ni2;
                    if (betterd(v1, i1, w2, j2)) { nv2 = v1; ni2 = i1; }
                    else                         { nv2 = w2; ni2 = j2; }
                    v1 = w1; i1 = j1; v2 = nv2; i2 = ni2;
                } else if (betterd(w1, j1, v2, i2)) { v2 = w1; i2 = j1; }
            }
            float sl = expf((float)(z - v1));
            float ssum = sl;
#pragma unroll
            for (int mm = 1; mm < 64; mm <<= 1) ssum += __shfl_xor(ssum, mm, 64);
            const float inv = 1.0f / ssum;
            if (e == 0) {
                const float s1 = fminf(fmaxf(inv, EPS_), 1.0f - EPS_);
                const float s2 = fminf(fmaxf(expf((float)(v2 - v1)) * inv, EPS_), 1.0f - EPS_);
                ts[row * 2 + 0] = s1;
                ts[row * 2 + 1] = s2;
                sel[row * 2 + 0] = i1;
                sel[row * 2 + 1] = i2;
            }
        }
        __syncthreads();
    }
}

// per-64-slot-chunk expert counts (transposed layout) + global histogram
__global__ void hist_chunks(const int* __restrict__ sel, int nchunks,
                            int* __restrict__ hist, int* __restrict__ cnt2)
{
    __shared__ int cnt[64];
    const int lane = threadIdx.x;   // 64
    const int c = blockIdx.x;
    cnt[lane] = 0;
    __syncthreads();
    const int ex = sel[c * 64 + lane];
    atomicAdd(&cnt[ex], 1);
    __syncthreads();
    cnt2[(size_t)lane * nchunks + c] = cnt[lane];
    if (cnt[lane]) atomicAdd(&hist[lane], cnt[lane]);
}

// per-batch rz sums (deterministic tree)
__global__ void rz_batch(const float* __restrict__ rzrow,
                         const int* __restrict__ bs_p, const int* __restrict__ sl_p,
                         double* __restrict__ bsum)
{
    __shared__ double red[256];
    const int nb = bs_p[0];
    const int seq = sl_p[0];
    for (int bb = blockIdx.x; bb < nb; bb += gridDim.x) {
        double s = 0.0;
        for (int i = threadIdx.x; i < seq; i += 256)
            s += (double)rzrow[(size_t)bb * seq + i];
        red[threadIdx.x] = s;
        __syncthreads();
        for (int st = 128; st > 0; st >>= 1) {
            if (threadIdx.x < st) red[threadIdx.x] += red[threadIdx.x + st];
            __syncthreads();
        }
        if (threadIdx.x == 0) bsum[bb] = red[0];
        __syncthreads();
    }
}

// expert starts (exclusive scan of hist) + out_cnt + rz finalize
__global__ void combine(const int* __restrict__ hist,
                        int* __restrict__ estart,
                        const double* __restrict__ bsum,
                        const int* __restrict__ bs_p,
                        float* __restrict__ out_cnt, float* __restrict__ out_rz)
{
    const int e = threadIdx.x;   // 64
    const int c0 = hist[e];
    int incl = c0;
#pragma unroll
    for (int mm = 1; mm < 64; mm <<= 1) {
        const int w = __shfl_up(incl, mm, 64);
        if (e >= mm) incl += w;
    }
    estart[e] = incl - c0;
    out_cnt[e] = (float)c0;
    if (e == 0) {
        const int nb = bs_p[0];
        double a = 0.0;
        for (int i = 0; i < nb; ++i) a += log(bsum[i]);
        out_rz[0] = (float)(a / nb);
    }
}

// parallel per-expert scan over chunks
__global__ __launch_bounds__(1024)
void chunk_scan(const int* __restrict__ cnt2, const int* __restrict__ estart,
                int nchunks, int* __restrict__ cbase)
{
    __shared__ int sc[1024];
    const int e = blockIdx.x;    // 64 blocks
    const int t = threadIdx.x;   // 1024
    const int v = (t < nchunks) ? cnt2[(size_t)e * nchunks + t] : 0;
    sc[t] = v;
    __syncthreads();
#pragma unroll
    for (int off = 1; off < 1024; off <<= 1) {
        const int add = (t >= off) ? sc[t - off] : 0;
        __syncthreads();
        sc[t] += add;
        __syncthreads();
    }
    if (t < nchunks)
        cbase[(size_t)t * 64 + e] = estart[e] + sc[t] - v;   // exclusive
}

// stable scatter per 64-slot chunk
__global__ void scatter(const int* __restrict__ sel, const float* __restrict__ ts,
                        const int* __restrict__ cbase,
                        float* __restrict__ out_sc, float* __restrict__ out_idx)
{
    __shared__ int shx[64];
    const int lane = threadIdx.x;   // 64
    const int c = blockIdx.x;
    const int idx = c * 64 + lane;
    const int ex = sel[idx];
    shx[lane] = ex;
    __syncthreads();
    int pre = 0;
#pragma unroll
    for (int j = 0; j < 64; ++j) pre += (int)((j < lane) && (shx[j] == ex));
    const int pos = cbase[c * 64 + ex] + pre;
    out_sc[pos]  = ts[idx];
    out_idx[pos] = (float)(idx >> 1);
}

extern "C" void kernel_launch(void* const* d_in, const int* in_sizes, int n_in,
                              void* d_out, int out_size, void* d_ws, size_t ws_size,
                              hipStream_t stream)
{
    const float* x = (const float*)d_in[0];
    const float* W = (const float*)d_in[1];
    const float* b = (const float*)d_in[2];
    const int* bs_p = (const int*)d_in[3];
    const int* sl_p = (const int*)d_in[4];

    const int E   = in_sizes[2];           // 64
    const int dim = in_sizes[1] / E;       // 2048
    const int N   = in_sizes[0] / dim;     // 16384
    const int total = N * 2;               // slots
    const int nchunks = total / 64;        // 512

    char* ws = (char*)d_ws;
    size_t off = 0;
    int*    hist     = (int*)(ws + off); off += 256;
    double* bsum     = (double*)(ws + off); off += 512;
    int*    nflags   = (int*)(ws + off); off += 256;
    int*    estart   = (int*)(ws + off); off += 256;
    float*  ts       = (float*)(ws + off); off += (size_t)total * 4;
    int*    sel      = (int*)(ws + off); off += (size_t)total * 4;
    int*    flaglist = (int*)(ws + off); off += (size_t)N * 4;
    float*  rzrow    = (float*)(ws + off); off += (size_t)N * 4;
    int*    cnt2     = (int*)(ws + off); off += (size_t)nchunks * 64 * 4;
    int*    cbase    = (int*)(ws + off); off += (size_t)nchunks * 64 * 4;
    unsigned short* wfg = (unsigned short*)(ws + off); off += (size_t)dim * 64 * 2 * 2;

    float* out_sc  = (float*)d_out;
    float* out_idx = out_sc + total;
    float* out_cnt = out_idx + total;
    float* out_rz  = out_cnt + E;

    hipMemsetAsync(ws, 0, 1280, stream);

    hipLaunchKernelGGL(wconv, dim3(dim * 64 / 256), dim3(256), 0, stream, W, wfg);
    hipLaunchKernelGGL(gemm_mfma, dim3(N / 64), dim3(256), 0, stream,
                       x, wfg, b, dim, N, ts, sel, rzrow, nflags, flaglist);
    hipLaunchKernelGGL(fixup, dim3(512), dim3(1024), 0, stream,
                       x, W, b, dim, nflags, flaglist, ts, sel);
    hipLaunchKernelGGL(hist_chunks, dim3(nchunks), dim3(64), 0, stream,
                       sel, nchunks, hist, cnt2);
    hipLaunchKernelGGL(rz_batch, dim3(64), dim3(256), 0, stream,
                       rzrow, bs_p, sl_p, bsum);
    hipLaunchKernelGGL(combine, dim3(1), dim3(64), 0, stream,
                       hist, estart, bsum, bs_p, out_cnt, out_rz);
    hipLaunchKernelGGL(chunk_scan, dim3(64), dim3(1024), 0, stream,
                       cnt2, estart, nchunks, cbase);
    hipLaunchKernelGGL(scatter, dim3(nchunks), dim3(64), 0, stream,
                       sel, ts, cbase, out_sc, out_idx);
}

// Round 16
// 102.796 us; speedup vs baseline: 1.2064x; 1.2064x over previous
//
#include <hip/hip_runtime.h>
#include <math.h>

#define EPS_ 1e-10f
#define MARGIN 4e-3f

typedef __attribute__((ext_vector_type(8))) short sh8;
typedef __attribute__((ext_vector_type(4))) float fx4;

__device__ __forceinline__ bool betterf(float v, int i, float w, int j) {
    return (v > w) || (v == w && i < j);
}
__device__ __forceinline__ bool betterd(double v, int i, double w, int j) {
    return (v > w) || (v == w && i < j);
}
__device__ __forceinline__ unsigned short f2bf(float f) {   // RNE
    unsigned u = __float_as_uint(f);
    u += 0x7fffu + ((u >> 16) & 1u);
    return (unsigned short)(u >> 16);
}
__device__ __forceinline__ float bf2f(unsigned short h) {
    return __uint_as_float(((unsigned)h) << 16);
}
__device__ __forceinline__ void cvt8(const float4 a, const float4 c, sh8& hi, sh8& lo) {
    const float v[8] = {a.x, a.y, a.z, a.w, c.x, c.y, c.z, c.w};
#pragma unroll
    for (int j = 0; j < 8; ++j) {
        const unsigned short h = f2bf(v[j]);
        hi[j] = (short)h;
        lo[j] = (short)f2bf(v[j] - bf2f(h));
    }
}
__device__ __forceinline__ void gload_lds16(const float* g, void* l) {
    __builtin_amdgcn_global_load_lds(
        (const __attribute__((address_space(1))) void*)g,
        (__attribute__((address_space(3))) void*)l, 16, 0, 0);
}

// ---------------------------------------------------------------------------
// One-time W conversion into B-fragment layout, bf16 hi/lo (layout verified).
// wf[((s*4+t)*2+hl)*512 + l*8 + j]; lane l=n+16*bq holds W[k=s*32+bq*8+j][e=t*16+n].
// ---------------------------------------------------------------------------
__global__ __launch_bounds__(256)
void wconv(const float* __restrict__ W, unsigned short* __restrict__ wf)
{
    const int gid = blockIdx.x * 256 + threadIdx.x;   // dim*64
    const int e = gid & 63, k = gid >> 6;
    const int s = k >> 5, kk = k & 31, bq = kk >> 3, j = kk & 7;
    const int t = e >> 4, n = e & 15;
    const int l = n + 16 * bq;
    const float w = W[(size_t)k * 64 + e];
    const unsigned short hi = f2bf(w);
    const unsigned short lo = f2bf(w - bf2f(hi));
    const size_t base = ((size_t)s * 4 + t) * 2;
    wf[(base + 0) * 512 + l * 8 + j] = hi;
    wf[(base + 1) * 512 + l * 8 + j] = lo;
}

// ---------------------------------------------------------------------------
// m97-style MFMA GEMM: block = 256 thr = 4 waves = 64 rows, K-slice dim/4.
// Per BK=64 step: x[64][64] fp32 (16KB) staged via global_load_lds
// (async DMA, pre-swizzled source chunk c^(row&15), linear LDS dest),
// double buffered, ONE barrier per step. Wave wv computes rows wv*16..+15
// (A-row = wv*16 + m — R15 bug was reading row m for all waves).
// Fragments read ds_read_b128 at chunk (c^m) -> <=2-way banks. cvt to
// bf16 hi/lo in regs, W fragments direct int4 (L1-hot), 24 MFMA/step/wave.
// Grid = kspl(4) x N/64(256) = 1024 blocks, 4 blocks/CU, 4 waves/SIMD.
// ---------------------------------------------------------------------------
#define KSPL 4
__global__ __launch_bounds__(256, 4)
void gemm_mfma(const float* __restrict__ x, const unsigned short* __restrict__ wfg,
               int dim, int N, float* __restrict__ zpart)
{
    __shared__ __align__(16) char xs[2][16384];   // [buf][64 rows][64 k fp32]

    const int tid  = threadIdx.x;
    const int lane = tid & 63;
    const int wv   = tid >> 6;
    const int rgs  = N / 64;
    const int ks   = blockIdx.x / rgs;
    const int rg   = blockIdx.x % rgs;
    const int r0   = rg * 64;
    const int kslice = dim / KSPL;            // 512
    const int k0   = ks * kslice;
    const int nstep = kslice / 64;            // 8

    const int m = lane & 15;                  // A-fragment row-in-16
    const int q = lane >> 4;                  // A-fragment k-quad
    const int arow = wv * 16 + m;             // wave's actual tile row

    // staging geometry: round r, wave wv, lane l covers
    // row = r*16 + wv*4 + (l>>4), LDS chunk = l&15, global chunk = (l&15)^(row&15)
    const int srow_lo = wv * 4 + (lane >> 4);       // + r*16
    const int schunk  = lane & 15;

    fx4 acc[4] = {};

    const unsigned short* wl8 = wfg + (size_t)(k0 >> 5) * 4096 + lane * 8;

    // prologue: stage step 0 into buf 0
#pragma unroll
    for (int r = 0; r < 4; ++r) {
        const int row = r * 16 + srow_lo;
        const int gc  = schunk ^ (row & 15);
        gload_lds16(x + (size_t)(r0 + row) * dim + k0 + gc * 4,
                    &xs[0][r * 4096 + wv * 1024]);
    }
    __syncthreads();

    for (int s = 0; s < nstep; ++s) {
        const int cb = s & 1;
        // stage step s+1 into other buffer (async, stays in flight)
        if (s + 1 < nstep) {
#pragma unroll
            for (int r = 0; r < 4; ++r) {
                const int row = r * 16 + srow_lo;
                const int gc  = schunk ^ (row & 15);
                gload_lds16(x + (size_t)(r0 + row) * dim + k0 + (s + 1) * 64 + gc * 4,
                            &xs[cb ^ 1][r * 4096 + wv * 1024]);
            }
        }
        // compute step s from buf cb: two K=32 halves; A row = arow
#pragma unroll
        for (int kk = 0; kk < 2; ++kk) {
            const int c0 = kk * 8 + q * 2;
            const float4 f0 = *(const float4*)&xs[cb][arow * 256 + ((c0 + 0) ^ m) * 16];
            const float4 f1 = *(const float4*)&xs[cb][arow * 256 + ((c0 + 1) ^ m) * 16];
            sh8 ah, al;
            cvt8(f0, f1, ah, al);
            const unsigned short* wk = wl8 + (size_t)(s * 2 + kk) * 4096;
#pragma unroll
            for (int te = 0; te < 4; ++te) {
                const sh8 bh = __builtin_bit_cast(sh8, *(const int4*)(wk + (te * 2 + 0) * 512));
                const sh8 bl = __builtin_bit_cast(sh8, *(const int4*)(wk + (te * 2 + 1) * 512));
                acc[te] = __builtin_amdgcn_mfma_f32_16x16x32_bf16(ah, bh, acc[te], 0, 0, 0);
                acc[te] = __builtin_amdgcn_mfma_f32_16x16x32_bf16(ah, bl, acc[te], 0, 0, 0);
                acc[te] = __builtin_amdgcn_mfma_f32_16x16x32_bf16(al, bh, acc[te], 0, 0, 0);
            }
        }
        __syncthreads();   // staging for s+1 complete; buffers separated
    }

    // store zpart[ks][row][e] (C layout: e-in-tile = lane&15, row-in-16 = (lane>>4)*4+i)
    const int n = lane & 15;
    const int g = lane >> 4;
    float* zp = zpart + ((size_t)ks * N + r0 + wv * 16) * 64;
#pragma unroll
    for (int te = 0; te < 4; ++te)
#pragma unroll
        for (int i = 0; i < 4; ++i)
            zp[(g * 4 + i) * 64 + te * 16 + n] = acc[te][i];
}

// ---------------------------------------------------------------------------
// Merge + fused epilogue: wave = 4 rows; lane = expert. Sums KSPL slices
// (fixed order) + bias, 64-lane butterfly top-2 / m3 / softmax / rz / flag.
// Grid = N/16 blocks x 256 thr.
// ---------------------------------------------------------------------------
__global__ __launch_bounds__(256)
void merge_epi(const float* __restrict__ zpart, const float* __restrict__ b,
               int N, float* __restrict__ ts, int* __restrict__ sel,
               float* __restrict__ rzrow,
               int* __restrict__ nflags, int* __restrict__ flaglist)
{
    const int lane = threadIdx.x & 63;
    const int wv   = threadIdx.x >> 6;
    const int e = lane;
    const float be = b[e];

    for (int rr = 0; rr < 4; ++rr) {
        const int row = blockIdx.x * 16 + wv * 4 + rr;
        float z = be;
#pragma unroll
        for (int ks = 0; ks < KSPL; ++ks)
            z += zpart[((size_t)ks * N + row) * 64 + e];

        float v1 = z, v2 = -3.4e38f;
        int i1 = e, i2 = 1 << 30;
#pragma unroll
        for (int mm = 1; mm < 64; mm <<= 1) {
            const float wva = __shfl_xor(v1, mm, 64); const int j1 = __shfl_xor(i1, mm, 64);
            const float wvb = __shfl_xor(v2, mm, 64); const int j2 = __shfl_xor(i2, mm, 64);
            if (betterf(wva, j1, v1, i1)) {
                float nv2; int ni2;
                if (betterf(v1, i1, wvb, j2)) { nv2 = v1; ni2 = i1; }
                else                          { nv2 = wvb; ni2 = j2; }
                v1 = wva; i1 = j1; v2 = nv2; i2 = ni2;
            } else if (betterf(wva, j1, v2, i2)) { v2 = wva; i2 = j1; }
        }

        float m3 = (e == i1 || e == i2) ? -3.4e38f : z;
#pragma unroll
        for (int mm = 1; mm < 64; mm <<= 1) m3 = fmaxf(m3, __shfl_xor(m3, mm, 64));

        const float ex = expf(z - v1);
        float ssum = ex;
#pragma unroll
        for (int mm = 1; mm < 64; mm <<= 1) ssum += __shfl_xor(ssum, mm, 64);
        const float inv = 1.0f / ssum;

        float sc = fminf(fmaxf(ex * inv, EPS_), 1.0f - EPS_);
        float srz = sc / (1.0f - sc);
#pragma unroll
        for (int mm = 1; mm < 64; mm <<= 1) srz += __shfl_xor(srz, mm, 64);

        if (e == 0) {
            const float s1 = fminf(fmaxf(inv, EPS_), 1.0f - EPS_);
            const float s2 = fminf(fmaxf(expf(v2 - v1) * inv, EPS_), 1.0f - EPS_);
            ts[row * 2 + 0] = s1;
            ts[row * 2 + 1] = s2;
            sel[row * 2 + 0] = i1;
            sel[row * 2 + 1] = i2;
            rzrow[row] = srz;
            if ((v1 - v2) < MARGIN || (v2 - m3) < MARGIN) {
                const int slot = atomicAdd(nflags, 1);
                flaglist[slot] = row;
            }
        }
    }
}

// ---------------------------------------------------------------------------
// fp64 recompute of flagged near-tie rows. 1024 thr = 64 e x 16 K-slices.
// ---------------------------------------------------------------------------
__global__ __launch_bounds__(1024)
void fixup(const float* __restrict__ x, const float* __restrict__ W,
           const float* __restrict__ b, int dim,
           const int* __restrict__ nflags, const int* __restrict__ flaglist,
           float* __restrict__ ts, int* __restrict__ sel)
{
    __shared__ double red[1024];
    const int tid = threadIdx.x;
    const int e = tid & 63;
    const int q = tid >> 6;              // 0..15
    const int nf = *nflags;
    const int slice = dim >> 4;          // 128

    for (int f = blockIdx.x; f < nf; f += gridDim.x) {
        const int row = flaglist[f];
        const float* xr = x + (size_t)row * dim;
        const int k0 = q * slice;
        double a0 = 0.0, a1 = 0.0, a2 = 0.0, a3 = 0.0;
        for (int k = k0; k < k0 + slice; k += 4) {
            a0 = fma((double)xr[k + 0], (double)W[(size_t)(k + 0) * 64 + e], a0);
            a1 = fma((double)xr[k + 1], (double)W[(size_t)(k + 1) * 64 + e], a1);
            a2 = fma((double)xr[k + 2], (double)W[(size_t)(k + 2) * 64 + e], a2);
            a3 = fma((double)xr[k + 3], (double)W[(size_t)(k + 3) * 64 + e], a3);
        }
        red[tid] = (a0 + a1) + (a2 + a3);
        __syncthreads();
        for (int st = 512; st >= 64; st >>= 1) {
            if (tid < st) red[tid] += red[tid + st];
            __syncthreads();
        }
        if (tid < 64) {
            const double z = red[tid] + (double)b[e];
            double v1 = z, v2 = -1e300;
            int i1 = e, i2 = 1 << 30;
#pragma unroll
            for (int mm = 1; mm < 64; mm <<= 1) {
                const double w1 = __shfl_xor(v1, mm, 64); const int j1 = __shfl_xor(i1, mm, 64);
                const double w2 = __shfl_xor(v2, mm, 64); const int j2 = __shfl_xor(i2, mm, 64);
                if (betterd(w1, j1, v1, i1)) {
                    double nv2; int ni2;
                    if (betterd(v1, i1, w2, j2)) { nv2 = v1; ni2 = i1; }
                    else                         { nv2 = w2; ni2 = j2; }
                    v1 = w1; i1 = j1; v2 = nv2; i2 = ni2;
                } else if (betterd(w1, j1, v2, i2)) { v2 = w1; i2 = j1; }
            }
            float sl = expf((float)(z - v1));
            float ssum = sl;
#pragma unroll
            for (int mm = 1; mm < 64; mm <<= 1) ssum += __shfl_xor(ssum, mm, 64);
            const float inv = 1.0f / ssum;
            if (e == 0) {
                const float s1 = fminf(fmaxf(inv, EPS_), 1.0f - EPS_);
                const float s2 = fminf(fmaxf(expf((float)(v2 - v1)) * inv, EPS_), 1.0f - EPS_);
                ts[row * 2 + 0] = s1;
                ts[row * 2 + 1] = s2;
                sel[row * 2 + 0] = i1;
                sel[row * 2 + 1] = i2;
            }
        }
        __syncthreads();
    }
}

// per-64-slot-chunk expert counts (transposed layout) + global histogram
__global__ void hist_chunks(const int* __restrict__ sel, int nchunks,
                            int* __restrict__ hist, int* __restrict__ cnt2)
{
    __shared__ int cnt[64];
    const int lane = threadIdx.x;   // 64
    const int c = blockIdx.x;
    cnt[lane] = 0;
    __syncthreads();
    const int ex = sel[c * 64 + lane];
    atomicAdd(&cnt[ex], 1);
    __syncthreads();
    cnt2[(size_t)lane * nchunks + c] = cnt[lane];
    if (cnt[lane]) atomicAdd(&hist[lane], cnt[lane]);
}

// per-batch rz sums (deterministic tree)
__global__ void rz_batch(const float* __restrict__ rzrow,
                         const int* __restrict__ bs_p, const int* __restrict__ sl_p,
                         double* __restrict__ bsum)
{
    __shared__ double red[256];
    const int nb = bs_p[0];
    const int seq = sl_p[0];
    for (int bb = blockIdx.x; bb < nb; bb += gridDim.x) {
        double s = 0.0;
        for (int i = threadIdx.x; i < seq; i += 256)
            s += (double)rzrow[(size_t)bb * seq + i];
        red[threadIdx.x] = s;
        __syncthreads();
        for (int st = 128; st > 0; st >>= 1) {
            if (threadIdx.x < st) red[threadIdx.x] += red[threadIdx.x + st];
            __syncthreads();
        }
        if (threadIdx.x == 0) bsum[bb] = red[0];
        __syncthreads();
    }
}

// expert starts (exclusive scan of hist) + out_cnt + rz finalize
__global__ void combine(const int* __restrict__ hist,
                        int* __restrict__ estart,
                        const double* __restrict__ bsum,
                        const int* __restrict__ bs_p,
                        float* __restrict__ out_cnt, float* __restrict__ out_rz)
{
    const int e = threadIdx.x;   // 64
    const int c0 = hist[e];
    int incl = c0;
#pragma unroll
    for (int mm = 1; mm < 64; mm <<= 1) {
        const int w = __shfl_up(incl, mm, 64);
        if (e >= mm) incl += w;
    }
    estart[e] = incl - c0;
    out_cnt[e] = (float)c0;
    if (e == 0) {
        const int nb = bs_p[0];
        double a = 0.0;
        for (int i = 0; i < nb; ++i) a += log(bsum[i]);
        out_rz[0] = (float)(a / nb);
    }
}

// parallel per-expert scan over chunks
__global__ __launch_bounds__(1024)
void chunk_scan(const int* __restrict__ cnt2, const int* __restrict__ estart,
                int nchunks, int* __restrict__ cbase)
{
    __shared__ int sc[1024];
    const int e = blockIdx.x;    // 64 blocks
    const int t = threadIdx.x;   // 1024
    const int v = (t < nchunks) ? cnt2[(size_t)e * nchunks + t] : 0;
    sc[t] = v;
    __syncthreads();
#pragma unroll
    for (int off = 1; off < 1024; off <<= 1) {
        const int add = (t >= off) ? sc[t - off] : 0;
        __syncthreads();
        sc[t] += add;
        __syncthreads();
    }
    if (t < nchunks)
        cbase[(size_t)t * 64 + e] = estart[e] + sc[t] - v;   // exclusive
}

// stable scatter per 64-slot chunk
__global__ void scatter(const int* __restrict__ sel, const float* __restrict__ ts,
                        const int* __restrict__ cbase,
                        float* __restrict__ out_sc, float* __restrict__ out_idx)
{
    __shared__ int shx[64];
    const int lane = threadIdx.x;   // 64
    const int c = blockIdx.x;
    const int idx = c * 64 + lane;
    const int ex = sel[idx];
    shx[lane] = ex;
    __syncthreads();
    int pre = 0;
#pragma unroll
    for (int j = 0; j < 64; ++j) pre += (int)((j < lane) && (shx[j] == ex));
    const int pos = cbase[c * 64 + ex] + pre;
    out_sc[pos]  = ts[idx];
    out_idx[pos] = (float)(idx >> 1);
}

extern "C" void kernel_launch(void* const* d_in, const int* in_sizes, int n_in,
                              void* d_out, int out_size, void* d_ws, size_t ws_size,
                              hipStream_t stream)
{
    const float* x = (const float*)d_in[0];
    const float* W = (const float*)d_in[1];
    const float* b = (const float*)d_in[2];
    const int* bs_p = (const int*)d_in[3];
    const int* sl_p = (const int*)d_in[4];

    const int E   = in_sizes[2];           // 64
    const int dim = in_sizes[1] / E;       // 2048
    const int N   = in_sizes[0] / dim;     // 16384
    const int total = N * 2;               // slots
    const int nchunks = total / 64;        // 512

    char* ws = (char*)d_ws;
    size_t off = 0;
    int*    hist     = (int*)(ws + off); off += 256;
    double* bsum     = (double*)(ws + off); off += 512;
    int*    nflags   = (int*)(ws + off); off += 256;
    int*    estart   = (int*)(ws + off); off += 256;
    float*  ts       = (float*)(ws + off); off += (size_t)total * 4;
    int*    sel      = (int*)(ws + off); off += (size_t)total * 4;
    int*    flaglist = (int*)(ws + off); off += (size_t)N * 4;
    float*  rzrow    = (float*)(ws + off); off += (size_t)N * 4;
    int*    cnt2     = (int*)(ws + off); off += (size_t)nchunks * 64 * 4;
    int*    cbase    = (int*)(ws + off); off += (size_t)nchunks * 64 * 4;
    unsigned short* wfg = (unsigned short*)(ws + off); off += (size_t)dim * 64 * 2 * 2;
    float*  zpart    = (float*)(ws + off); off += (size_t)KSPL * N * 64 * 4;

    float* out_sc  = (float*)d_out;
    float* out_idx = out_sc + total;
    float* out_cnt = out_idx + total;
    float* out_rz  = out_cnt + E;

    hipMemsetAsync(ws, 0, 1280, stream);

    hipLaunchKernelGGL(wconv, dim3(dim * 64 / 256), dim3(256), 0, stream, W, wfg);
    hipLaunchKernelGGL(gemm_mfma, dim3((N / 64) * KSPL), dim3(256), 0, stream,
                       x, wfg, dim, N, zpart);
    hipLaunchKernelGGL(merge_epi, dim3(N / 16), dim3(256), 0, stream,
                       zpart, b, N, ts, sel, rzrow, nflags, flaglist);
    hipLaunchKernelGGL(fixup, dim3(512), dim3(1024), 0, stream,
                       x, W, b, dim, nflags, flaglist, ts, sel);
    hipLaunchKernelGGL(hist_chunks, dim3(nchunks), dim3(64), 0, stream,
                       sel, nchunks, hist, cnt2);
    hipLaunchKernelGGL(rz_batch, dim3(64), dim3(256), 0, stream,
                       rzrow, bs_p, sl_p, bsum);
    hipLaunchKernelGGL(combine, dim3(1), dim3(64), 0, stream,
                       hist, estart, bsum, bs_p, out_cnt, out_rz);
    hipLaunchKernelGGL(chunk_scan, dim3(64), dim3(1024), 0, stream,
                       cnt2, estart, nchunks, cbase);
    hipLaunchKernelGGL(scatter, dim3(nchunks), dim3(64), 0, stream,
                       sel, ts, cbase, out_sc, out_idx);
}

// Round 17
// 95.247 us; speedup vs baseline: 1.3021x; 1.0793x over previous
//
#include <hip/hip_runtime.h>
#include <math.h>

#define EPS_ 1e-10f
#define MARGIN 4e-3f

typedef __attribute__((ext_vector_type(8))) short sh8;
typedef __attribute__((ext_vector_type(4))) float fx4;

__device__ __forceinline__ bool betterf(float v, int i, float w, int j) {
    return (v > w) || (v == w && i < j);
}
__device__ __forceinline__ bool betterd(double v, int i, double w, int j) {
    return (v > w) || (v == w && i < j);
}
__device__ __forceinline__ unsigned short f2bf(float f) {   // RNE
    unsigned u = __float_as_uint(f);
    u += 0x7fffu + ((u >> 16) & 1u);
    return (unsigned short)(u >> 16);
}
__device__ __forceinline__ float bf2f(unsigned short h) {
    return __uint_as_float(((unsigned)h) << 16);
}
__device__ __forceinline__ void cvt8(const float4 a, const float4 c, sh8& hi, sh8& lo) {
    const float v[8] = {a.x, a.y, a.z, a.w, c.x, c.y, c.z, c.w};
#pragma unroll
    for (int j = 0; j < 8; ++j) {
        const unsigned short h = f2bf(v[j]);
        hi[j] = (short)h;
        lo[j] = (short)f2bf(v[j] - bf2f(h));
    }
}
__device__ __forceinline__ void gload_lds16(const void* g, void* l) {
    __builtin_amdgcn_global_load_lds(
        (const __attribute__((address_space(1))) void*)g,
        (__attribute__((address_space(3))) void*)l, 16, 0, 0);
}

// ---------------------------------------------------------------------------
// One-time W conversion into B-fragment layout, bf16 hi/lo (layout verified).
// wf[((s*4+t)*2+hl)*512 + l*8 + j]; lane l=n+16*bq holds W[k=s*32+bq*8+j][e=t*16+n].
// ---------------------------------------------------------------------------
__global__ __launch_bounds__(256)
void wconv(const float* __restrict__ W, unsigned short* __restrict__ wf)
{
    const int gid = blockIdx.x * 256 + threadIdx.x;   // dim*64
    const int e = gid & 63, k = gid >> 6;
    const int s = k >> 5, kk = k & 31, bq = kk >> 3, j = kk & 7;
    const int t = e >> 4, n = e & 15;
    const int l = n + 16 * bq;
    const float w = W[(size_t)k * 64 + e];
    const unsigned short hi = f2bf(w);
    const unsigned short lo = f2bf(w - bf2f(hi));
    const size_t base = ((size_t)s * 4 + t) * 2;
    wf[(base + 0) * 512 + l * 8 + j] = hi;
    wf[(base + 1) * 512 + l * 8 + j] = lo;
}

// ---------------------------------------------------------------------------
// MFMA GEMM with BOTH operands LDS-staged (the W-traffic fix):
// block = 256 thr = 4 waves = 64 rows, K-slice dim/4. Per K=32 step:
//   x[64][32] fp32 (8KB) staged via global_load_lds (pre-swizzled source
//     chunk c^(row&7), linear LDS dest), fragment reads at chunk^(m&7);
//   W step-fragments (8KB) staged via global_load_lds LINEAR — W re-reads
//     now come from LDS (per-CU) instead of L3. Cache W traffic drops
//     512MB -> 128MB (1024 blocks x 128KB), which WAS the 75us invariant.
// Double-buffered, one barrier per step. Grid = 4 x 256 = 1024 blocks,
// 32KB LDS -> 4 blocks/CU, 4 waves/SIMD.
// ---------------------------------------------------------------------------
#define KSPL 4
__global__ __launch_bounds__(256, 4)
void gemm_mfma(const float* __restrict__ x, const unsigned short* __restrict__ wfg,
               int dim, int N, float* __restrict__ zpart)
{
    __shared__ __align__(16) char xs[2][8192];    // [buf][64 rows][32 k fp32]
    __shared__ __align__(16) char wls[2][8192];   // [buf][one K=32 W step]

    const int tid  = threadIdx.x;
    const int lane = tid & 63;
    const int wv   = tid >> 6;
    const int rgs  = N / 64;
    const int ks   = blockIdx.x / rgs;
    const int rg   = blockIdx.x % rgs;
    const int r0   = rg * 64;
    const int kslice = dim / KSPL;            // 512
    const int k0   = ks * kslice;
    const int nstep = kslice / 32;            // 16

    const int m = lane & 15;                  // A-fragment row-in-16
    const int q = lane >> 4;                  // A-fragment k-quad
    const int arow = wv * 16 + m;             // wave's tile row
    const int mk = m & 7;                     // swizzle key

    // x staging: round r, lane l covers row = wv*16 + r*8 + (l>>3),
    // global chunk gc = (l&7) ^ (row&7); LDS linear (chunk l&7).
    const int srow_in = lane >> 3;            // 0..7
    const int sgc     = (lane & 7) ^ (srow_in & 7);

    fx4 acc[4] = {};

    const char* wbytes = (const char*)wfg;
    const size_t wstep0 = (size_t)(k0 >> 5) * 8192;   // byte base of this slice

    // ---- prologue: stage step 0 into buf 0 ----
#pragma unroll
    for (int r = 0; r < 2; ++r) {
        const int row = wv * 16 + r * 8 + srow_in;
        gload_lds16(x + (size_t)(r0 + row) * dim + k0 + sgc * 4,
                    &xs[0][(wv * 16 + r * 8) * 128]);
        gload_lds16(wbytes + wstep0 + wv * 2048 + r * 1024 + lane * 16,
                    &wls[0][wv * 2048 + r * 1024]);
    }
    __syncthreads();

    for (int s = 0; s < nstep; ++s) {
        const int cb = s & 1;
        // stage step s+1 (async; drained by the vmcnt before next barrier)
        if (s + 1 < nstep) {
#pragma unroll
            for (int r = 0; r < 2; ++r) {
                const int row = wv * 16 + r * 8 + srow_in;
                gload_lds16(x + (size_t)(r0 + row) * dim + k0 + (s + 1) * 32 + sgc * 4,
                            &xs[cb ^ 1][(wv * 16 + r * 8) * 128]);
                gload_lds16(wbytes + wstep0 + (size_t)(s + 1) * 8192
                                  + wv * 2048 + r * 1024 + lane * 16,
                            &wls[cb ^ 1][wv * 2048 + r * 1024]);
            }
        }
        // compute step s: x frags (swizzled), W frags (linear, from LDS)
        {
            const float4 f0 = *(const float4*)&xs[cb][arow * 128 + ((2 * q + 0) ^ mk) * 16];
            const float4 f1 = *(const float4*)&xs[cb][arow * 128 + ((2 * q + 1) ^ mk) * 16];
            sh8 ah, al;
            cvt8(f0, f1, ah, al);
#pragma unroll
            for (int te = 0; te < 4; ++te) {
                const sh8 bh = __builtin_bit_cast(sh8,
                    *(const int4*)&wls[cb][(te * 2 + 0) * 1024 + lane * 16]);
                const sh8 bl = __builtin_bit_cast(sh8,
                    *(const int4*)&wls[cb][(te * 2 + 1) * 1024 + lane * 16]);
                acc[te] = __builtin_amdgcn_mfma_f32_16x16x32_bf16(ah, bh, acc[te], 0, 0, 0);
                acc[te] = __builtin_amdgcn_mfma_f32_16x16x32_bf16(ah, bl, acc[te], 0, 0, 0);
                acc[te] = __builtin_amdgcn_mfma_f32_16x16x32_bf16(al, bh, acc[te], 0, 0, 0);
            }
        }
        __syncthreads();
    }

    // store zpart[ks][row][e] (C layout: e-in-tile = lane&15, row-in-16 = (lane>>4)*4+i)
    const int n = lane & 15;
    const int g = lane >> 4;
    float* zp = zpart + ((size_t)ks * N + r0 + wv * 16) * 64;
#pragma unroll
    for (int te = 0; te < 4; ++te)
#pragma unroll
        for (int i = 0; i < 4; ++i)
            zp[(g * 4 + i) * 64 + te * 16 + n] = acc[te][i];
}

// ---------------------------------------------------------------------------
// Merge + fused epilogue: wave = 4 rows; lane = expert. Sums KSPL slices
// (fixed order) + bias, 64-lane butterfly top-2 / m3 / softmax / rz / flag.
// ---------------------------------------------------------------------------
__global__ __launch_bounds__(256)
void merge_epi(const float* __restrict__ zpart, const float* __restrict__ b,
               int N, float* __restrict__ ts, int* __restrict__ sel,
               float* __restrict__ rzrow,
               int* __restrict__ nflags, int* __restrict__ flaglist)
{
    const int lane = threadIdx.x & 63;
    const int wv   = threadIdx.x >> 6;
    const int e = lane;
    const float be = b[e];

    for (int rr = 0; rr < 4; ++rr) {
        const int row = blockIdx.x * 16 + wv * 4 + rr;
        float z = be;
#pragma unroll
        for (int ks = 0; ks < KSPL; ++ks)
            z += zpart[((size_t)ks * N + row) * 64 + e];

        float v1 = z, v2 = -3.4e38f;
        int i1 = e, i2 = 1 << 30;
#pragma unroll
        for (int mm = 1; mm < 64; mm <<= 1) {
            const float wva = __shfl_xor(v1, mm, 64); const int j1 = __shfl_xor(i1, mm, 64);
            const float wvb = __shfl_xor(v2, mm, 64); const int j2 = __shfl_xor(i2, mm, 64);
            if (betterf(wva, j1, v1, i1)) {
                float nv2; int ni2;
                if (betterf(v1, i1, wvb, j2)) { nv2 = v1; ni2 = i1; }
                else                          { nv2 = wvb; ni2 = j2; }
                v1 = wva; i1 = j1; v2 = nv2; i2 = ni2;
            } else if (betterf(wva, j1, v2, i2)) { v2 = wva; i2 = j1; }
        }

        float m3 = (e == i1 || e == i2) ? -3.4e38f : z;
#pragma unroll
        for (int mm = 1; mm < 64; mm <<= 1) m3 = fmaxf(m3, __shfl_xor(m3, mm, 64));

        const float ex = expf(z - v1);
        float ssum = ex;
#pragma unroll
        for (int mm = 1; mm < 64; mm <<= 1) ssum += __shfl_xor(ssum, mm, 64);
        const float inv = 1.0f / ssum;

        float sc = fminf(fmaxf(ex * inv, EPS_), 1.0f - EPS_);
        float srz = sc / (1.0f - sc);
#pragma unroll
        for (int mm = 1; mm < 64; mm <<= 1) srz += __shfl_xor(srz, mm, 64);

        if (e == 0) {
            const float s1 = fminf(fmaxf(inv, EPS_), 1.0f - EPS_);
            const float s2 = fminf(fmaxf(expf(v2 - v1) * inv, EPS_), 1.0f - EPS_);
            ts[row * 2 + 0] = s1;
            ts[row * 2 + 1] = s2;
            sel[row * 2 + 0] = i1;
            sel[row * 2 + 1] = i2;
            rzrow[row] = srz;
            if ((v1 - v2) < MARGIN || (v2 - m3) < MARGIN) {
                const int slot = atomicAdd(nflags, 1);
                flaglist[slot] = row;
            }
        }
    }
}

// ---------------------------------------------------------------------------
// fp64 recompute of flagged near-tie rows. 1024 thr = 64 e x 16 K-slices.
// ---------------------------------------------------------------------------
__global__ __launch_bounds__(1024)
void fixup(const float* __restrict__ x, const float* __restrict__ W,
           const float* __restrict__ b, int dim,
           const int* __restrict__ nflags, const int* __restrict__ flaglist,
           float* __restrict__ ts, int* __restrict__ sel)
{
    __shared__ double red[1024];
    const int tid = threadIdx.x;
    const int e = tid & 63;
    const int q = tid >> 6;              // 0..15
    const int nf = *nflags;
    const int slice = dim >> 4;          // 128

    for (int f = blockIdx.x; f < nf; f += gridDim.x) {
        const int row = flaglist[f];
        const float* xr = x + (size_t)row * dim;
        const int k0 = q * slice;
        double a0 = 0.0, a1 = 0.0, a2 = 0.0, a3 = 0.0;
        for (int k = k0; k < k0 + slice; k += 4) {
            a0 = fma((double)xr[k + 0], (double)W[(size_t)(k + 0) * 64 + e], a0);
            a1 = fma((double)xr[k + 1], (double)W[(size_t)(k + 1) * 64 + e], a1);
            a2 = fma((double)xr[k + 2], (double)W[(size_t)(k + 2) * 64 + e], a2);
            a3 = fma((double)xr[k + 3], (double)W[(size_t)(k + 3) * 64 + e], a3);
        }
        red[tid] = (a0 + a1) + (a2 + a3);
        __syncthreads();
        for (int st = 512; st >= 64; st >>= 1) {
            if (tid < st) red[tid] += red[tid + st];
            __syncthreads();
        }
        if (tid < 64) {
            const double z = red[tid] + (double)b[e];
            double v1 = z, v2 = -1e300;
            int i1 = e, i2 = 1 << 30;
#pragma unroll
            for (int mm = 1; mm < 64; mm <<= 1) {
                const double w1 = __shfl_xor(v1, mm, 64); const int j1 = __shfl_xor(i1, mm, 64);
                const double w2 = __shfl_xor(v2, mm, 64); const int j2 = __shfl_xor(i2, mm, 64);
                if (betterd(w1, j1, v1, i1)) {
                    double nv2; int ni2;
                    if (betterd(v1, i1, w2, j2)) { nv2 = v1; ni2 = i1; }
                    else                         { nv2 = w2; ni2 = j2; }
                    v1 = w1; i1 = j1; v2 = nv2; i2 = ni2;
                } else if (betterd(w1, j1, v2, i2)) { v2 = w1; i2 = j1; }
            }
            float sl = expf((float)(z - v1));
            float ssum = sl;
#pragma unroll
            for (int mm = 1; mm < 64; mm <<= 1) ssum += __shfl_xor(ssum, mm, 64);
            const float inv = 1.0f / ssum;
            if (e == 0) {
                const float s1 = fminf(fmaxf(inv, EPS_), 1.0f - EPS_);
                const float s2 = fminf(fmaxf(expf((float)(v2 - v1)) * inv, EPS_), 1.0f - EPS_);
                ts[row * 2 + 0] = s1;
                ts[row * 2 + 1] = s2;
                sel[row * 2 + 0] = i1;
                sel[row * 2 + 1] = i2;
            }
        }
        __syncthreads();
    }
}

// per-64-slot-chunk expert counts (transposed layout) + global histogram
__global__ void hist_chunks(const int* __restrict__ sel, int nchunks,
                            int* __restrict__ hist, int* __restrict__ cnt2)
{
    __shared__ int cnt[64];
    const int lane = threadIdx.x;   // 64
    const int c = blockIdx.x;
    cnt[lane] = 0;
    __syncthreads();
    const int ex = sel[c * 64 + lane];
    atomicAdd(&cnt[ex], 1);
    __syncthreads();
    cnt2[(size_t)lane * nchunks + c] = cnt[lane];
    if (cnt[lane]) atomicAdd(&hist[lane], cnt[lane]);
}

// per-batch rz sums (deterministic tree)
__global__ void rz_batch(const float* __restrict__ rzrow,
                         const int* __restrict__ bs_p, const int* __restrict__ sl_p,
                         double* __restrict__ bsum)
{
    __shared__ double red[256];
    const int nb = bs_p[0];
    const int seq = sl_p[0];
    for (int bb = blockIdx.x; bb < nb; bb += gridDim.x) {
        double s = 0.0;
        for (int i = threadIdx.x; i < seq; i += 256)
            s += (double)rzrow[(size_t)bb * seq + i];
        red[threadIdx.x] = s;
        __syncthreads();
        for (int st = 128; st > 0; st >>= 1) {
            if (threadIdx.x < st) red[threadIdx.x] += red[threadIdx.x + st];
            __syncthreads();
        }
        if (threadIdx.x == 0) bsum[bb] = red[0];
        __syncthreads();
    }
}

// expert starts (exclusive scan of hist) + out_cnt + rz finalize
__global__ void combine(const int* __restrict__ hist,
                        int* __restrict__ estart,
                        const double* __restrict__ bsum,
                        const int* __restrict__ bs_p,
                        float* __restrict__ out_cnt, float* __restrict__ out_rz)
{
    const int e = threadIdx.x;   // 64
    const int c0 = hist[e];
    int incl = c0;
#pragma unroll
    for (int mm = 1; mm < 64; mm <<= 1) {
        const int w = __shfl_up(incl, mm, 64);
        if (e >= mm) incl += w;
    }
    estart[e] = incl - c0;
    out_cnt[e] = (float)c0;
    if (e == 0) {
        const int nb = bs_p[0];
        double a = 0.0;
        for (int i = 0; i < nb; ++i) a += log(bsum[i]);
        out_rz[0] = (float)(a / nb);
    }
}

// parallel per-expert scan over chunks
__global__ __launch_bounds__(1024)
void chunk_scan(const int* __restrict__ cnt2, const int* __restrict__ estart,
                int nchunks, int* __restrict__ cbase)
{
    __shared__ int sc[1024];
    const int e = blockIdx.x;    // 64 blocks
    const int t = threadIdx.x;   // 1024
    const int v = (t < nchunks) ? cnt2[(size_t)e * nchunks + t] : 0;
    sc[t] = v;
    __syncthreads();
#pragma unroll
    for (int off = 1; off < 1024; off <<= 1) {
        const int add = (t >= off) ? sc[t - off] : 0;
        __syncthreads();
        sc[t] += add;
        __syncthreads();
    }
    if (t < nchunks)
        cbase[(size_t)t * 64 + e] = estart[e] + sc[t] - v;   // exclusive
}

// stable scatter per 64-slot chunk
__global__ void scatter(const int* __restrict__ sel, const float* __restrict__ ts,
                        const int* __restrict__ cbase,
                        float* __restrict__ out_sc, float* __restrict__ out_idx)
{
    __shared__ int shx[64];
    const int lane = threadIdx.x;   // 64
    const int c = blockIdx.x;
    const int idx = c * 64 + lane;
    const int ex = sel[idx];
    shx[lane] = ex;
    __syncthreads();
    int pre = 0;
#pragma unroll
    for (int j = 0; j < 64; ++j) pre += (int)((j < lane) && (shx[j] == ex));
    const int pos = cbase[c * 64 + ex] + pre;
    out_sc[pos]  = ts[idx];
    out_idx[pos] = (float)(idx >> 1);
}

extern "C" void kernel_launch(void* const* d_in, const int* in_sizes, int n_in,
                              void* d_out, int out_size, void* d_ws, size_t ws_size,
                              hipStream_t stream)
{
    const float* x = (const float*)d_in[0];
    const float* W = (const float*)d_in[1];
    const float* b = (const float*)d_in[2];
    const int* bs_p = (const int*)d_in[3];
    const int* sl_p = (const int*)d_in[4];

    const int E   = in_sizes[2];           // 64
    const int dim = in_sizes[1] / E;       // 2048
    const int N   = in_sizes[0] / dim;     // 16384
    const int total = N * 2;               // slots
    const int nchunks = total / 64;        // 512

    char* ws = (char*)d_ws;
    size_t off = 0;
    int*    hist     = (int*)(ws + off); off += 256;
    double* bsum     = (double*)(ws + off); off += 512;
    int*    nflags   = (int*)(ws + off); off += 256;
    int*    estart   = (int*)(ws + off); off += 256;
    float*  ts       = (float*)(ws + off); off += (size_t)total * 4;
    int*    sel      = (int*)(ws + off); off += (size_t)total * 4;
    int*    flaglist = (int*)(ws + off); off += (size_t)N * 4;
    float*  rzrow    = (float*)(ws + off); off += (size_t)N * 4;
    int*    cnt2     = (int*)(ws + off); off += (size_t)nchunks * 64 * 4;
    int*    cbase    = (int*)(ws + off); off += (size_t)nchunks * 64 * 4;
    unsigned short* wfg = (unsigned short*)(ws + off); off += (size_t)dim * 64 * 2 * 2;
    float*  zpart    = (float*)(ws + off); off += (size_t)KSPL * N * 64 * 4;

    float* out_sc  = (float*)d_out;
    float* out_idx = out_sc + total;
    float* out_cnt = out_idx + total;
    float* out_rz  = out_cnt + E;

    hipMemsetAsync(ws, 0, 1280, stream);

    hipLaunchKernelGGL(wconv, dim3(dim * 64 / 256), dim3(256), 0, stream, W, wfg);
    hipLaunchKernelGGL(gemm_mfma, dim3((N / 64) * KSPL), dim3(256), 0, stream,
                       x, wfg, dim, N, zpart);
    hipLaunchKernelGGL(merge_epi, dim3(N / 16), dim3(256), 0, stream,
                       zpart, b, N, ts, sel, rzrow, nflags, flaglist);
    hipLaunchKernelGGL(fixup, dim3(512), dim3(1024), 0, stream,
                       x, W, b, dim, nflags, flaglist, ts, sel);
    hipLaunchKernelGGL(hist_chunks, dim3(nchunks), dim3(64), 0, stream,
                       sel, nchunks, hist, cnt2);
    hipLaunchKernelGGL(rz_batch, dim3(64), dim3(256), 0, stream,
                       rzrow, bs_p, sl_p, bsum);
    hipLaunchKernelGGL(combine, dim3(1), dim3(64), 0, stream,
                       hist, estart, bsum, bs_p, out_cnt, out_rz);
    hipLaunchKernelGGL(chunk_scan, dim3(64), dim3(1024), 0, stream,
                       cnt2, estart, nchunks, cbase);
    hipLaunchKernelGGL(scatter, dim3(nchunks), dim3(64), 0, stream,
                       sel, ts, cbase, out_sc, out_idx);
}

// Round 18
// 90.416 us; speedup vs baseline: 1.3716x; 1.0534x over previous
//
#include <hip/hip_runtime.h>
#include <math.h>

#define EPS_ 1e-10f
#define MARGIN 4e-3f

typedef __attribute__((ext_vector_type(8))) short sh8;
typedef __attribute__((ext_vector_type(4))) float fx4;

__device__ __forceinline__ bool betterf(float v, int i, float w, int j) {
    return (v > w) || (v == w && i < j);
}
__device__ __forceinline__ bool betterd(double v, int i, double w, int j) {
    return (v > w) || (v == w && i < j);
}
__device__ __forceinline__ unsigned short f2bf(float f) {   // RNE
    unsigned u = __float_as_uint(f);
    u += 0x7fffu + ((u >> 16) & 1u);
    return (unsigned short)(u >> 16);
}
__device__ __forceinline__ float bf2f(unsigned short h) {
    return __uint_as_float(((unsigned)h) << 16);
}
__device__ __forceinline__ void cvt8(const float4 a, const float4 c, sh8& hi, sh8& lo) {
    const float v[8] = {a.x, a.y, a.z, a.w, c.x, c.y, c.z, c.w};
#pragma unroll
    for (int j = 0; j < 8; ++j) {
        const unsigned short h = f2bf(v[j]);
        hi[j] = (short)h;
        lo[j] = (short)f2bf(v[j] - bf2f(h));
    }
}
__device__ __forceinline__ void gload_lds16(const void* g, void* l) {
    __builtin_amdgcn_global_load_lds(
        (const __attribute__((address_space(1))) void*)g,
        (__attribute__((address_space(3))) void*)l, 16, 0, 0);
}

// ---------------------------------------------------------------------------
// One-time W conversion into B-fragment layout, bf16 hi/lo (layout verified).
// ---------------------------------------------------------------------------
__global__ __launch_bounds__(256)
void wconv(const float* __restrict__ W, unsigned short* __restrict__ wf)
{
    const int gid = blockIdx.x * 256 + threadIdx.x;   // dim*64
    const int e = gid & 63, k = gid >> 6;
    const int s = k >> 5, kk = k & 31, bq = kk >> 3, j = kk & 7;
    const int t = e >> 4, n = e & 15;
    const int l = n + 16 * bq;
    const float w = W[(size_t)k * 64 + e];
    const unsigned short hi = f2bf(w);
    const unsigned short lo = f2bf(w - bf2f(hi));
    const size_t base = ((size_t)s * 4 + t) * 2;
    wf[(base + 0) * 512 + l * 8 + j] = hi;
    wf[(base + 1) * 512 + l * 8 + j] = lo;
}

// ---------------------------------------------------------------------------
// MFMA GEMM, both operands LDS-staged (R17, unchanged — verified).
// ---------------------------------------------------------------------------
#define KSPL 4
__global__ __launch_bounds__(256, 4)
void gemm_mfma(const float* __restrict__ x, const unsigned short* __restrict__ wfg,
               int dim, int N, float* __restrict__ zpart)
{
    __shared__ __align__(16) char xs[2][8192];    // [buf][64 rows][32 k fp32]
    __shared__ __align__(16) char wls[2][8192];   // [buf][one K=32 W step]

    const int tid  = threadIdx.x;
    const int lane = tid & 63;
    const int wv   = tid >> 6;
    const int rgs  = N / 64;
    const int ks   = blockIdx.x / rgs;
    const int rg   = blockIdx.x % rgs;
    const int r0   = rg * 64;
    const int kslice = dim / KSPL;            // 512
    const int k0   = ks * kslice;
    const int nstep = kslice / 32;            // 16

    const int m = lane & 15;
    const int q = lane >> 4;
    const int arow = wv * 16 + m;
    const int mk = m & 7;

    const int srow_in = lane >> 3;            // 0..7
    const int sgc     = (lane & 7) ^ (srow_in & 7);

    fx4 acc[4] = {};

    const char* wbytes = (const char*)wfg;
    const size_t wstep0 = (size_t)(k0 >> 5) * 8192;

#pragma unroll
    for (int r = 0; r < 2; ++r) {
        const int row = wv * 16 + r * 8 + srow_in;
        gload_lds16(x + (size_t)(r0 + row) * dim + k0 + sgc * 4,
                    &xs[0][(wv * 16 + r * 8) * 128]);
        gload_lds16(wbytes + wstep0 + wv * 2048 + r * 1024 + lane * 16,
                    &wls[0][wv * 2048 + r * 1024]);
    }
    __syncthreads();

    for (int s = 0; s < nstep; ++s) {
        const int cb = s & 1;
        if (s + 1 < nstep) {
#pragma unroll
            for (int r = 0; r < 2; ++r) {
                const int row = wv * 16 + r * 8 + srow_in;
                gload_lds16(x + (size_t)(r0 + row) * dim + k0 + (s + 1) * 32 + sgc * 4,
                            &xs[cb ^ 1][(wv * 16 + r * 8) * 128]);
                gload_lds16(wbytes + wstep0 + (size_t)(s + 1) * 8192
                                  + wv * 2048 + r * 1024 + lane * 16,
                            &wls[cb ^ 1][wv * 2048 + r * 1024]);
            }
        }
        {
            const float4 f0 = *(const float4*)&xs[cb][arow * 128 + ((2 * q + 0) ^ mk) * 16];
            const float4 f1 = *(const float4*)&xs[cb][arow * 128 + ((2 * q + 1) ^ mk) * 16];
            sh8 ah, al;
            cvt8(f0, f1, ah, al);
#pragma unroll
            for (int te = 0; te < 4; ++te) {
                const sh8 bh = __builtin_bit_cast(sh8,
                    *(const int4*)&wls[cb][(te * 2 + 0) * 1024 + lane * 16]);
                const sh8 bl = __builtin_bit_cast(sh8,
                    *(const int4*)&wls[cb][(te * 2 + 1) * 1024 + lane * 16]);
                acc[te] = __builtin_amdgcn_mfma_f32_16x16x32_bf16(ah, bh, acc[te], 0, 0, 0);
                acc[te] = __builtin_amdgcn_mfma_f32_16x16x32_bf16(ah, bl, acc[te], 0, 0, 0);
                acc[te] = __builtin_amdgcn_mfma_f32_16x16x32_bf16(al, bh, acc[te], 0, 0, 0);
            }
        }
        __syncthreads();
    }

    const int n = lane & 15;
    const int g = lane >> 4;
    float* zp = zpart + ((size_t)ks * N + r0 + wv * 16) * 64;
#pragma unroll
    for (int te = 0; te < 4; ++te)
#pragma unroll
        for (int i = 0; i < 4; ++i)
            zp[(g * 4 + i) * 64 + te * 16 + n] = acc[te][i];
}

// ---------------------------------------------------------------------------
// Fused merge + epilogue + per-chunk histogram + per-batch rz:
// block = 1 chunk = 32 rows (4 waves x 8 rows); lane = expert.
// Writes ts/sel/flaglist, cnt2[e][c], atomic hist, atomic fp64 bsum[batch].
// ---------------------------------------------------------------------------
__global__ __launch_bounds__(256)
void merge_epi32(const float* __restrict__ zpart, const float* __restrict__ b,
                 const int* __restrict__ sl_p, int N, int nchunks,
                 float* __restrict__ ts, int* __restrict__ sel,
                 int* __restrict__ nflags, int* __restrict__ flaglist,
                 int* __restrict__ hist, int* __restrict__ cnt2,
                 double* __restrict__ bsum)
{
    __shared__ int cnt[64];
    __shared__ float rsum[4];

    const int tid  = threadIdx.x;
    const int lane = tid & 63;
    const int wv   = tid >> 6;
    const int c    = blockIdx.x;          // chunk
    const int e    = lane;
    const float be = b[e];

    if (tid < 64) cnt[tid] = 0;
    __syncthreads();

    float myrz = 0.0f;

    for (int rr = 0; rr < 8; ++rr) {
        const int row = c * 32 + wv * 8 + rr;
        float z = be;
#pragma unroll
        for (int ks = 0; ks < KSPL; ++ks)
            z += zpart[((size_t)ks * N + row) * 64 + e];

        float v1 = z, v2 = -3.4e38f;
        int i1 = e, i2 = 1 << 30;
#pragma unroll
        for (int mm = 1; mm < 64; mm <<= 1) {
            const float wva = __shfl_xor(v1, mm, 64); const int j1 = __shfl_xor(i1, mm, 64);
            const float wvb = __shfl_xor(v2, mm, 64); const int j2 = __shfl_xor(i2, mm, 64);
            if (betterf(wva, j1, v1, i1)) {
                float nv2; int ni2;
                if (betterf(v1, i1, wvb, j2)) { nv2 = v1; ni2 = i1; }
                else                          { nv2 = wvb; ni2 = j2; }
                v1 = wva; i1 = j1; v2 = nv2; i2 = ni2;
            } else if (betterf(wva, j1, v2, i2)) { v2 = wva; i2 = j1; }
        }

        float m3 = (e == i1 || e == i2) ? -3.4e38f : z;
#pragma unroll
        for (int mm = 1; mm < 64; mm <<= 1) m3 = fmaxf(m3, __shfl_xor(m3, mm, 64));

        const float ex = expf(z - v1);
        float ssum = ex;
#pragma unroll
        for (int mm = 1; mm < 64; mm <<= 1) ssum += __shfl_xor(ssum, mm, 64);
        const float inv = 1.0f / ssum;

        float sc = fminf(fmaxf(ex * inv, EPS_), 1.0f - EPS_);
        float srz = sc / (1.0f - sc);
#pragma unroll
        for (int mm = 1; mm < 64; mm <<= 1) srz += __shfl_xor(srz, mm, 64);

        if (e == 0) {
            const float s1 = fminf(fmaxf(inv, EPS_), 1.0f - EPS_);
            const float s2 = fminf(fmaxf(expf(v2 - v1) * inv, EPS_), 1.0f - EPS_);
            ts[row * 2 + 0] = s1;
            ts[row * 2 + 1] = s2;
            sel[row * 2 + 0] = i1;
            sel[row * 2 + 1] = i2;
            atomicAdd(&cnt[i1], 1);
            atomicAdd(&cnt[i2], 1);
            myrz += srz;
            if ((v1 - v2) < MARGIN || (v2 - m3) < MARGIN) {
                const int slot = atomicAdd(nflags, 1);
                flaglist[slot] = row;
            }
        }
    }

    if (lane == 0) rsum[wv] = myrz;
    __syncthreads();

    if (tid < 64) {
        cnt2[(size_t)tid * nchunks + c] = cnt[tid];
        if (cnt[tid]) atomicAdd(&hist[tid], cnt[tid]);
    }
    if (tid == 0) {
        const int seq = sl_p[0];
        const int batch = (c * 32) / seq;
        atomicAdd(&bsum[batch], (double)(rsum[0] + rsum[1] + rsum[2] + rsum[3]));
    }
}

// ---------------------------------------------------------------------------
// fp64 recompute of flagged near-tie rows + count-delta fixup of hist/cnt2.
// ---------------------------------------------------------------------------
__global__ __launch_bounds__(1024)
void fixup(const float* __restrict__ x, const float* __restrict__ W,
           const float* __restrict__ b, int dim, int nchunks,
           const int* __restrict__ nflags, const int* __restrict__ flaglist,
           float* __restrict__ ts, int* __restrict__ sel,
           int* __restrict__ hist, int* __restrict__ cnt2)
{
    __shared__ double red[1024];
    const int tid = threadIdx.x;
    const int e = tid & 63;
    const int q = tid >> 6;              // 0..15
    const int nf = *nflags;
    const int slice = dim >> 4;          // 128

    for (int f = blockIdx.x; f < nf; f += gridDim.x) {
        const int row = flaglist[f];
        const float* xr = x + (size_t)row * dim;
        const int k0 = q * slice;
        double a0 = 0.0, a1 = 0.0, a2 = 0.0, a3 = 0.0;
        for (int k = k0; k < k0 + slice; k += 4) {
            a0 = fma((double)xr[k + 0], (double)W[(size_t)(k + 0) * 64 + e], a0);
            a1 = fma((double)xr[k + 1], (double)W[(size_t)(k + 1) * 64 + e], a1);
            a2 = fma((double)xr[k + 2], (double)W[(size_t)(k + 2) * 64 + e], a2);
            a3 = fma((double)xr[k + 3], (double)W[(size_t)(k + 3) * 64 + e], a3);
        }
        red[tid] = (a0 + a1) + (a2 + a3);
        __syncthreads();
        for (int st = 512; st >= 64; st >>= 1) {
            if (tid < st) red[tid] += red[tid + st];
            __syncthreads();
        }
        if (tid < 64) {
            const double z = red[tid] + (double)b[e];
            double v1 = z, v2 = -1e300;
            int i1 = e, i2 = 1 << 30;
#pragma unroll
            for (int mm = 1; mm < 64; mm <<= 1) {
                const double w1 = __shfl_xor(v1, mm, 64); const int j1 = __shfl_xor(i1, mm, 64);
                const double w2 = __shfl_xor(v2, mm, 64); const int j2 = __shfl_xor(i2, mm, 64);
                if (betterd(w1, j1, v1, i1)) {
                    double nv2; int ni2;
                    if (betterd(v1, i1, w2, j2)) { nv2 = v1; ni2 = i1; }
                    else                         { nv2 = w2; ni2 = j2; }
                    v1 = w1; i1 = j1; v2 = nv2; i2 = ni2;
                } else if (betterd(w1, j1, v2, i2)) { v2 = w1; i2 = j1; }
            }
            float sl = expf((float)(z - v1));
            float ssum = sl;
#pragma unroll
            for (int mm = 1; mm < 64; mm <<= 1) ssum += __shfl_xor(ssum, mm, 64);
            const float inv = 1.0f / ssum;
            if (e == 0) {
                const float s1 = fminf(fmaxf(inv, EPS_), 1.0f - EPS_);
                const float s2 = fminf(fmaxf(expf((float)(v2 - v1)) * inv, EPS_), 1.0f - EPS_);
                const int o1 = sel[row * 2 + 0];
                const int o2 = sel[row * 2 + 1];
                ts[row * 2 + 0] = s1;
                ts[row * 2 + 1] = s2;
                if (o1 != i1 || o2 != i2) {
                    sel[row * 2 + 0] = i1;
                    sel[row * 2 + 1] = i2;
                    const int c = row >> 5;       // 32 rows per chunk
                    atomicSub(&hist[o1], 1); atomicSub(&hist[o2], 1);
                    atomicAdd(&hist[i1], 1); atomicAdd(&hist[i2], 1);
                    atomicSub(&cnt2[(size_t)o1 * nchunks + c], 1);
                    atomicSub(&cnt2[(size_t)o2 * nchunks + c], 1);
                    atomicAdd(&cnt2[(size_t)i1 * nchunks + c], 1);
                    atomicAdd(&cnt2[(size_t)i2 * nchunks + c], 1);
                }
            }
        }
        __syncthreads();
    }
}

// ---------------------------------------------------------------------------
// scan2: per-expert chunk scan + expert starts + out_cnt + rz finalize.
// Block e: estart from hist prefix, Hillis-Steele over cnt2[e][*].
// ---------------------------------------------------------------------------
__global__ __launch_bounds__(1024)
void scan2(const int* __restrict__ hist, const int* __restrict__ cnt2,
           int nchunks, int* __restrict__ cbase,
           const double* __restrict__ bsum, const int* __restrict__ bs_p,
           float* __restrict__ out_cnt, float* __restrict__ out_rz)
{
    __shared__ int sc[1024];
    __shared__ int es;
    const int e = blockIdx.x;    // 64 blocks
    const int t = threadIdx.x;   // 1024

    if (t == 0) {
        int s = 0;
        for (int i = 0; i < e; ++i) s += hist[i];
        es = s;
        out_cnt[e] = (float)hist[e];
        if (e == 0) {
            const int nb = bs_p[0];
            double a = 0.0;
            for (int i = 0; i < nb; ++i) a += log(bsum[i]);
            out_rz[0] = (float)(a / nb);
        }
    }
    const int v = (t < nchunks) ? cnt2[(size_t)e * nchunks + t] : 0;
    sc[t] = v;
    __syncthreads();
#pragma unroll
    for (int off = 1; off < 1024; off <<= 1) {
        const int add = (t >= off) ? sc[t - off] : 0;
        __syncthreads();
        sc[t] += add;
        __syncthreads();
    }
    if (t < nchunks)
        cbase[(size_t)t * 64 + e] = es + sc[t] - v;   // exclusive
}

// stable scatter per 64-slot chunk
__global__ void scatter(const int* __restrict__ sel, const float* __restrict__ ts,
                        const int* __restrict__ cbase,
                        float* __restrict__ out_sc, float* __restrict__ out_idx)
{
    __shared__ int shx[64];
    const int lane = threadIdx.x;   // 64
    const int c = blockIdx.x;
    const int idx = c * 64 + lane;
    const int ex = sel[idx];
    shx[lane] = ex;
    __syncthreads();
    int pre = 0;
#pragma unroll
    for (int j = 0; j < 64; ++j) pre += (int)((j < lane) && (shx[j] == ex));
    const int pos = cbase[c * 64 + ex] + pre;
    out_sc[pos]  = ts[idx];
    out_idx[pos] = (float)(idx >> 1);
}

extern "C" void kernel_launch(void* const* d_in, const int* in_sizes, int n_in,
                              void* d_out, int out_size, void* d_ws, size_t ws_size,
                              hipStream_t stream)
{
    const float* x = (const float*)d_in[0];
    const float* W = (const float*)d_in[1];
    const float* b = (const float*)d_in[2];
    const int* bs_p = (const int*)d_in[3];
    const int* sl_p = (const int*)d_in[4];

    const int E   = in_sizes[2];           // 64
    const int dim = in_sizes[1] / E;       // 2048
    const int N   = in_sizes[0] / dim;     // 16384
    const int total = N * 2;               // slots
    const int nchunks = total / 64;        // 512

    char* ws = (char*)d_ws;
    size_t off = 0;
    int*    hist     = (int*)(ws + off); off += 256;
    double* bsum     = (double*)(ws + off); off += 512;
    int*    nflags   = (int*)(ws + off); off += 256;
    float*  ts       = (float*)(ws + off); off += (size_t)total * 4;
    int*    sel      = (int*)(ws + off); off += (size_t)total * 4;
    int*    flaglist = (int*)(ws + off); off += (size_t)N * 4;
    int*    cnt2     = (int*)(ws + off); off += (size_t)nchunks * 64 * 4;
    int*    cbase    = (int*)(ws + off); off += (size_t)nchunks * 64 * 4;
    unsigned short* wfg = (unsigned short*)(ws + off); off += (size_t)dim * 64 * 2 * 2;
    float*  zpart    = (float*)(ws + off); off += (size_t)KSPL * N * 64 * 4;

    float* out_sc  = (float*)d_out;
    float* out_idx = out_sc + total;
    float* out_cnt = out_idx + total;
    float* out_rz  = out_cnt + E;

    hipMemsetAsync(ws, 0, 1024, stream);

    hipLaunchKernelGGL(wconv, dim3(dim * 64 / 256), dim3(256), 0, stream, W, wfg);
    hipLaunchKernelGGL(gemm_mfma, dim3((N / 64) * KSPL), dim3(256), 0, stream,
                       x, wfg, dim, N, zpart);
    hipLaunchKernelGGL(merge_epi32, dim3(nchunks), dim3(256), 0, stream,
                       zpart, b, sl_p, N, nchunks, ts, sel, nflags, flaglist,
                       hist, cnt2, bsum);
    hipLaunchKernelGGL(fixup, dim3(512), dim3(1024), 0, stream,
                       x, W, b, dim, nchunks, nflags, flaglist, ts, sel, hist, cnt2);
    hipLaunchKernelGGL(scan2, dim3(64), dim3(1024), 0, stream,
                       hist, cnt2, nchunks, cbase, bsum, bs_p, out_cnt, out_rz);
    hipLaunchKernelGGL(scatter, dim3(nchunks), dim3(64), 0, stream,
                       sel, ts, cbase, out_sc, out_idx);
}